// Round 1
// 485.810 us; speedup vs baseline: 1.0225x; 1.0225x over previous
//
#include <hip/hip_runtime.h>
#include <hip/hip_bf16.h>

// LocalGNN forward, 4-kernel fused pipeline (latency-hiding rework).
// h_{p+1} = D (G+I) D h_p  computed as  acc = (G+I)bf16 @ (d_j h_p,j)bf16, h=d_i*acc.
// K0: G fp32 -> direct global->reg frag pack (no LDS round trip), rowsum via shfl,
//     (G+I) bf16 A-frag swizzle + x B-frags + W frags.
// K1/K2: prop pass (16-row blocks, 4-way K-split, 2-deep prefetch) -> hrow_p + hF_p.
// K3: prop pass 3 + fused [x,h1,h2,h3] @ W^T + bias epilogue (all 4 waves).
// B=4, N=4096, DIM=64. fp32 in/out, bf16 MFMA internally.

typedef __attribute__((ext_vector_type(4))) float  floatx4;
typedef __attribute__((ext_vector_type(8))) short  short8;

#define NB 4
#define NN 4096
#define ND 64
#define HF_B 262144   // shorts per batch in hF: 128 kc * 4 c * 64 ln * 8

__device__ __forceinline__ unsigned short f2bf_bits(float v) {
    __hip_bfloat16 b = __float2bfloat16(v);
    return *reinterpret_cast<unsigned short*>(&b);
}
__device__ __forceinline__ float bf2f(unsigned short u) {
    unsigned int x = ((unsigned int)u) << 16;
    return *reinterpret_cast<float*>(&x);
}
__device__ __forceinline__ short8 pack8p(const float* v) {
    short8 r;
#pragma unroll
    for (int j = 0; j < 8; ++j) r[j] = (short)f2bf_bits(v[j]);
    return r;
}

// ================================================================ K0
// block = tile tt (b, mt16): 16 rows x 4096 cols of G. No LDS staging:
// thread (w,lane) owns frag (kcl=gg*4+w, ln=lane) per 512-col chunk, loads its
// 32B row segment directly, accumulates rowsum in-register, packs +I, stores.
__global__ __launch_bounds__(256, 4) void prep_graph(const float* __restrict__ g,
                                                     const float* __restrict__ x,
                                                     const float* __restrict__ W,
                                                     float* __restrict__ dinv,
                                                     unsigned short* __restrict__ gswz,
                                                     unsigned short* __restrict__ hF0,
                                                     unsigned short* __restrict__ Wf) {
    __shared__ float rsum[4][16];
    __shared__ float dl[16];
    int tt = blockIdx.x;                 // 0..1023
    int b = tt >> 8, mt = tt & 255;
    int t = threadIdx.x;
    int w = t >> 6, lane = t & 63;
    int m = lane & 15, q = lane >> 4;
    const float* rowp = g + ((size_t)b * NN + mt * 16 + m) * NN;
    size_t outbase = (size_t)tt * 128 * 512;
    int i_row = mt * 16 + m;
    float rs = 0.f;

    for (int s0 = 0; s0 < NN; s0 += 512) {
#pragma unroll
        for (int gg = 0; gg < 4; ++gg) {
            int kcl = gg * 4 + w;                        // 0..15, wave-uniform
            int kbase = s0 + kcl * 32 + q * 8;
            floatx4 v0 = *reinterpret_cast<const floatx4*>(rowp + kbase);
            floatx4 v1 = *reinterpret_cast<const floatx4*>(rowp + kbase + 4);
            float v[8];
#pragma unroll
            for (int j = 0; j < 4; ++j) { v[j] = v0[j]; v[4 + j] = v1[j]; }
            float s = 0.f;
#pragma unroll
            for (int j = 0; j < 8; ++j) s += v[j];
            rs += s;                                     // rowsum BEFORE +I
            int dj = i_row - kbase;
            if (dj >= 0 && dj < 8) v[dj] += 1.0f;        // +I
            *reinterpret_cast<short8*>(gswz + outbase + ((size_t)((s0 >> 5) + kcl)) * 512 + (size_t)lane * 8) = pack8p(v);
        }
    }
    // rowsum reduce: lanes {m, m+16, m+32, m+48} hold partials of row m
    rs += __shfl_xor(rs, 16);
    rs += __shfl_xor(rs, 32);
    if (lane < 16) rsum[w][lane] = rs;
    __syncthreads();
    if (t < 16) {
        float tot = rsum[0][t] + rsum[1][t] + rsum[2][t] + rsum[3][t];
        float d = 1.0f / (sqrtf(tot + 1.0f) + 1e-7f);    // +1.0 accounts for I
        dinv[b * NN + mt * 16 + t] = d;
        dl[t] = d;
    }
    __syncthreads();
    // this tile's half-window of hF0 = d_j * x_j  (kc = mt>>1, parity mt&1)
    if (t < 128) {
        int c = t >> 5, lnl = t & 31;
        int q_loc = lnl >> 4, mm = lnl & 15;
        int u = mt & 1, kc2 = mt >> 1;
        int ln = u * 32 + lnl;
        const float* xp = x + ((size_t)b * NN + mt * 16) * ND + c * 16 + mm;
        float v[8];
#pragma unroll
        for (int j = 0; j < 8; ++j) {
            int lr = q_loc * 8 + j;                      // 0..15
            v[j] = dl[lr] * xp[(size_t)lr * ND];
        }
        *reinterpret_cast<short8*>(hF0 + (size_t)b * HF_B + ((size_t)(kc2 * 4 + c) * 64 + ln) * 8) = pack8p(v);
    }
    // W -> B-frag layout (block 0 only): Wf[kc][c][ln][8] = W[c*16+m][kc*32+q*8+j]
    if (tt == 0) {
#pragma unroll
        for (int e = 0; e < 8; ++e) {
            int wi = e * 256 + t;                        // 0..2047
            int kc2 = wi >> 8;
            int c = (wi >> 6) & 3;
            int ln = wi & 63;
            int mm = ln & 15, qq = ln >> 4;
            float v[8];
#pragma unroll
            for (int j = 0; j < 8; ++j) v[j] = W[(size_t)(c * 16 + mm) * 256 + kc2 * 32 + qq * 8 + j];
            *reinterpret_cast<short8*>(Wf + ((size_t)(kc2 * 4 + c) * 64 + ln) * 8) = pack8p(v);
        }
    }
}

// ================================================================ prop core
// block = one 16-row tile (grid 1024 -> 4 blocks/CU, 16 waves/CU).
// wave w handles K-chunk [w*1024, (w+1)*1024): 32 kc iters, 2-deep prefetch.
// Tail prefetch over-reads <=4KB past the logical buffer (stays inside d_ws).
#define PROP_MAIN()                                                                      \
    int bid = blockIdx.x;                                                                \
    int b = bid >> 8, mk = bid & 255;                                                    \
    int t = threadIdx.x;                                                                 \
    int w = t >> 6, lane = t & 63;                                                       \
    int m = lane & 15, q = lane >> 4;                                                    \
    const unsigned short* Ap = gswz + ((size_t)(b * 256 + mk) * 128 + w * 32) * 512 + (size_t)lane * 8; \
    const unsigned short* Bp = hFin + (size_t)b * HF_B + (size_t)(w * 32) * 2048 + (size_t)lane * 8;    \
    floatx4 acc[4];                                                                      \
    _Pragma("unroll")                                                                    \
    for (int c = 0; c < 4; ++c) acc[c] = (floatx4){0.f, 0.f, 0.f, 0.f};                  \
    short8 a_c  = *reinterpret_cast<const short8*>(Ap);                                  \
    short8 b0_c = *reinterpret_cast<const short8*>(Bp);                                  \
    short8 b1_c = *reinterpret_cast<const short8*>(Bp + 512);                            \
    short8 b2_c = *reinterpret_cast<const short8*>(Bp + 1024);                           \
    short8 b3_c = *reinterpret_cast<const short8*>(Bp + 1536);                           \
    _Pragma("unroll 2")                                                                  \
    for (int kc = 0; kc < 32; ++kc) {                                                    \
        Ap += 512; Bp += 2048;                                                           \
        short8 a_n  = *reinterpret_cast<const short8*>(Ap);                              \
        short8 b0_n = *reinterpret_cast<const short8*>(Bp);                              \
        short8 b1_n = *reinterpret_cast<const short8*>(Bp + 512);                        \
        short8 b2_n = *reinterpret_cast<const short8*>(Bp + 1024);                       \
        short8 b3_n = *reinterpret_cast<const short8*>(Bp + 1536);                       \
        acc[0] = __builtin_amdgcn_mfma_f32_16x16x32_bf16(a_c, b0_c, acc[0], 0, 0, 0);    \
        acc[1] = __builtin_amdgcn_mfma_f32_16x16x32_bf16(a_c, b1_c, acc[1], 0, 0, 0);    \
        acc[2] = __builtin_amdgcn_mfma_f32_16x16x32_bf16(a_c, b2_c, acc[2], 0, 0, 0);    \
        acc[3] = __builtin_amdgcn_mfma_f32_16x16x32_bf16(a_c, b3_c, acc[3], 0, 0, 0);    \
        a_c = a_n; b0_c = b0_n; b1_c = b1_n; b2_c = b2_n; b3_c = b3_n;                   \
    }                                                                                    \
    if (t < 16) dl[t] = dinv[b * NN + mk * 16 + t];                                      \
    _Pragma("unroll")                                                                    \
    for (int c = 0; c < 4; ++c)                                                          \
        _Pragma("unroll")                                                                \
        for (int r = 0; r < 4; ++r) buf[w][q * 4 + r][c * 16 + m] = acc[c][r];           \
    __syncthreads();                                                                     \
    _Pragma("unroll")                                                                    \
    for (int e = 0; e < 4; ++e) {                                                        \
        int idx = e * 256 + t;                                                           \
        int r = idx >> 6, col = idx & 63;                                                \
        float s = buf[0][r][col] + buf[1][r][col] + buf[2][r][col] + buf[3][r][col];     \
        hsh[r][col] = f2bf_bits(dl[r] * s);                                              \
    }                                                                                    \
    __syncthreads();

// K1/K2: emit hrow_p + hF_p
__global__ __launch_bounds__(256, 4) void prop_pass(const unsigned short* __restrict__ gswz,
                                                    const unsigned short* __restrict__ hFin,
                                                    const float* __restrict__ dinv,
                                                    unsigned short* __restrict__ hrow,
                                                    unsigned short* __restrict__ hFout) {
    __shared__ float buf[4][16][68];
    __shared__ unsigned short hsh[16][64];
    __shared__ float dl[16];
    PROP_MAIN()
    // hrow: coalesced bf16 store of 16x64
    {
        unsigned short* hp = hrow + ((size_t)b * NN + mk * 16) * ND;
#pragma unroll
        for (int e = 0; e < 4; ++e) {
            int idx = e * 256 + t;
            hp[idx] = hsh[idx >> 6][idx & 63];
        }
    }
    // hF: half-window kc = mk>>1, parity mk&1; value = d_j * h_j
    if (t < 128) {
        int c = t >> 5, lnl = t & 31;
        int q_loc = lnl >> 4, mm = lnl & 15;
        int u = mk & 1, kc2 = mk >> 1;
        int ln = u * 32 + lnl;
        float v[8];
#pragma unroll
        for (int j = 0; j < 8; ++j) {
            int lr = q_loc * 8 + j;                      // 0..15
            v[j] = dl[lr] * bf2f(hsh[lr][c * 16 + mm]);
        }
        *reinterpret_cast<short8*>(hFout + (size_t)b * HF_B + ((size_t)(kc2 * 4 + c) * 64 + ln) * 8) = pack8p(v);
    }
}

// K3: pass 3 + fused final linear: out = [x,h1,h2,h3] @ W^T + bias
// wave w owns output col-block w (16 cols), full K=256 per wave -> no reduce.
__global__ __launch_bounds__(256, 4) void prop_final(const unsigned short* __restrict__ gswz,
                                                     const unsigned short* __restrict__ hFin,
                                                     const float* __restrict__ dinv,
                                                     const float* __restrict__ x,
                                                     const unsigned short* __restrict__ hrow1,
                                                     const unsigned short* __restrict__ hrow2,
                                                     const unsigned short* __restrict__ Wf,
                                                     const float* __restrict__ bias,
                                                     float* __restrict__ out) {
    __shared__ float buf[4][16][68];
    __shared__ unsigned short hsh[16][64];
    __shared__ float dl[16];
    PROP_MAIN()
    {
        int grow_r = b * NN + mk * 16 + m;               // A row for this lane
        floatx4 facc = (floatx4){0.f, 0.f, 0.f, 0.f};
#pragma unroll
        for (int p = 0; p < 4; ++p) {
#pragma unroll
            for (int ki = 0; ki < 2; ++ki) {
                short8 af;
                if (p == 0) {
                    const float* xp = x + (size_t)grow_r * ND + ki * 32 + q * 8;
                    float v[8];
#pragma unroll
                    for (int j = 0; j < 8; ++j) v[j] = xp[j];
                    af = pack8p(v);
                } else if (p == 1) {
                    af = *reinterpret_cast<const short8*>(hrow1 + (size_t)grow_r * ND + ki * 32 + q * 8);
                } else if (p == 2) {
                    af = *reinterpret_cast<const short8*>(hrow2 + (size_t)grow_r * ND + ki * 32 + q * 8);
                } else {
                    af = *reinterpret_cast<const short8*>(&hsh[m][ki * 32 + q * 8]);
                }
                int kc2 = p * 2 + ki;
                short8 bf = *reinterpret_cast<const short8*>(Wf + ((size_t)(kc2 * 4 + w) * 64 + lane) * 8);
                facc = __builtin_amdgcn_mfma_f32_16x16x32_bf16(af, bf, facc, 0, 0, 0);
            }
        }
        float bb = bias[w * 16 + m];
#pragma unroll
        for (int r = 0; r < 4; ++r) {
            int row = b * NN + mk * 16 + q * 4 + r;
            out[(size_t)row * ND + w * 16 + m] = facc[r] + bb;
        }
    }
}

// ================================================================ launch
extern "C" void kernel_launch(void* const* d_in, const int* in_sizes, int n_in,
                              void* d_out, int out_size, void* d_ws, size_t ws_size,
                              hipStream_t stream) {
    const float* x     = (const float*)d_in[0];
    const float* graph = (const float*)d_in[1];
    const float* W     = (const float*)d_in[2];
    const float* bias  = (const float*)d_in[3];
    float* out = (float*)d_out;

    // workspace layout (bytes)
    char* w = (char*)d_ws;
    float*          dinv  = (float*)w;                         //  64 KB
    unsigned short* Wf    = (unsigned short*)(w + (1 << 16));  //  16 KB
    unsigned short* hFa   = (unsigned short*)(w + (1 << 17));  //   2 MB
    unsigned short* hFb   = hFa + (size_t)NB * HF_B;           //   2 MB
    unsigned short* hrow1 = hFb + (size_t)NB * HF_B;           //   2 MB
    unsigned short* hrow2 = hrow1 + (size_t)NB * NN * ND;      //   2 MB
    unsigned short* gswz  = hrow2 + (size_t)NB * NN * ND;      // 134 MB

    prep_graph<<<1024, 256, 0, stream>>>(graph, x, W, dinv, gswz, hFa, Wf);
    prop_pass<<<1024, 256, 0, stream>>>(gswz, hFa, dinv, hrow1, hFb);
    prop_pass<<<1024, 256, 0, stream>>>(gswz, hFb, dinv, hrow2, hFa);
    prop_final<<<1024, 256, 0, stream>>>(gswz, hFa, dinv, x, hrow1, hrow2, Wf, bias, out);
}